// Round 6
// baseline (200.305 us; speedup 1.0000x reference)
//
#include <hip/hip_runtime.h>

// ---------------------------------------------------------------------------
// memory_tree: fused bf16-MFMA MLP (13->300->600->100->13) + cosine-sim max.
// R6: BM=128 (grid 512, 1 block/CU, LDS 152KB), af-register-cache (each
// wave's L2 A-fragments loaded once: 20 bf16x8 = 80 VGPR, kills 80% of h1
// LDS reads), halved weight L2-restream, SW=15 swizzle on h2/h3 (SW=7 left
// rows r/r+8 aliasing -> 4-way conflicts). No VGPR cap -> no spill.
// ---------------------------------------------------------------------------

typedef __bf16 bf16x8 __attribute__((ext_vector_type(8)));
typedef float f32x4 __attribute__((ext_vector_type(4)));
typedef float f32x16 __attribute__((ext_vector_type(16)));

// ---- workspace layout (bytes) ---------------------------------------------
constexpr size_t OFF_W1B = 0;                    // frag-order [10][2][64][8] bf16
constexpr size_t OFF_W2B = 20480;                // frag-order [20][20][64][8] bf16
constexpr size_t OFF_W3B = 430080;               // frag-order [4][40][64][8] bf16
constexpr size_t OFF_W4B = 593920;               // [32][128] bf16 (row layout)
constexpr size_t OFF_B1  = 602112;               // [320] f32
constexpr size_t OFF_B2  = 603392;               // [640] f32
constexpr size_t OFF_B3  = 605952;               // [128] f32
constexpr size_t OFF_B4  = 606464;               // [32]  f32
constexpr size_t OFF_T2N = 606720;               // [2048][32] bf16
constexpr size_t OFF_T1N = 737792;               // [65536][32] bf16
constexpr size_t OFF_PART= 4932096;              // [64][2048] f32 = 524288
// total: 5456384 bytes (~5.2 MB)

__device__ __forceinline__ bf16x8 ld8(const __bf16* p) {
    return *reinterpret_cast<const bf16x8*>(p);
}
__device__ __forceinline__ f32x4 mfma16(bf16x8 a, bf16x8 b, f32x4 c) {
    return __builtin_amdgcn_mfma_f32_16x16x32_bf16(a, b, c, 0, 0, 0);
}
__device__ __forceinline__ f32x16 mfma32(bf16x8 a, bf16x8 b, f32x16 c) {
    return __builtin_amdgcn_mfma_f32_32x32x16_bf16(a, b, c, 0, 0, 0);
}
// XOR bank-swizzle on 16B slots within a row
template<int SW>
__device__ __forceinline__ int swcol(int row, int col) {
    return (((col >> 3) ^ (row & SW)) << 3) | (col & 7);
}

// ---------------------------------------------------------------------------
// prep: weights -> bf16 (W1/W2/W3 in MFMA fragment order), biases, t2n
// ---------------------------------------------------------------------------
__global__ void prep_kernel(const float* __restrict__ W1, const float* __restrict__ b1,
                            const float* __restrict__ W2, const float* __restrict__ b2,
                            const float* __restrict__ W3, const float* __restrict__ b3,
                            const float* __restrict__ W4, const float* __restrict__ b4,
                            const float* __restrict__ value, char* __restrict__ ws) {
    __bf16* W1B = (__bf16*)(ws + OFF_W1B);
    __bf16* W2B = (__bf16*)(ws + OFF_W2B);
    __bf16* W3B = (__bf16*)(ws + OFF_W3B);
    __bf16* W4B = (__bf16*)(ws + OFF_W4B);
    float*  B1  = (float*)(ws + OFF_B1);
    float*  B2  = (float*)(ws + OFF_B2);
    float*  B3  = (float*)(ws + OFF_B3);
    float*  B4  = (float*)(ws + OFF_B4);
    __bf16* T2N = (__bf16*)(ws + OFF_T2N);

    int idx = blockIdx.x * 256 + threadIdx.x;
    if (idx < 10240) {                       // W1B frag order [nt<10][ks<2][lane][8]
        int e = idx & 7, lane = (idx >> 3) & 63, r = idx >> 9;
        int ks = r & 1, nt = r >> 1;
        int n = nt*32 + (lane & 31);
        int k = ks*16 + (lane >> 5)*8 + e;
        W1B[idx] = (__bf16)((n < 300 && k < 13) ? W1[n*13 + k] : 0.0f);
        return;
    }
    idx -= 10240;
    if (idx < 204800) {                      // W2B frag order [nt<20][ks<20][lane][8]
        int e = idx & 7, lane = (idx >> 3) & 63, r = idx >> 9;
        int ks = r % 20, nt = r / 20;
        int n = nt*32 + (lane & 31);
        int k = ks*16 + (lane >> 5)*8 + e;
        W2B[idx] = (__bf16)((n < 600 && k < 300) ? W2[n*300 + k] : 0.0f);
        return;
    }
    idx -= 204800;
    if (idx < 81920) {                       // W3B frag order [nt<4][ks<40][lane][8]
        int e = idx & 7, lane = (idx >> 3) & 63, r = idx >> 9;
        int ks = r % 40, nt = r / 40;
        int n = nt*32 + (lane & 31);
        int k = ks*16 + (lane >> 5)*8 + e;
        W3B[idx] = (__bf16)((n < 100 && k < 600) ? W3[n*600 + k] : 0.0f);
        return;
    }
    idx -= 81920;
    if (idx < 4096) {                        // W4B [32][128] row layout
        int n = idx >> 7, k = idx & 127;
        W4B[idx] = (__bf16)((n < 13 && k < 100) ? W4[n*100 + k] : 0.0f);
        return;
    }
    idx -= 4096;
    if (idx < 320) { B1[idx] = idx < 300 ? b1[idx] : 0.0f; return; }
    idx -= 320;
    if (idx < 640) { B2[idx] = idx < 600 ? b2[idx] : 0.0f; return; }
    idx -= 640;
    if (idx < 128) { B3[idx] = idx < 100 ? b3[idx] : 0.0f; return; }
    idx -= 128;
    if (idx < 32)  { B4[idx] = idx < 13  ? b4[idx] : 0.0f; return; }
    idx -= 32;
    if (idx < 2048) {                        // t2n rows
        float v[13]; float s = 0.0f;
        #pragma unroll
        for (int k = 0; k < 13; k++) { v[k] = value[idx*13 + k]; s += v[k]*v[k]; }
        float inv = 1.0f / fmaxf(sqrtf(s), 1e-8f);
        #pragma unroll
        for (int k = 0; k < 13; k++) T2N[idx*32 + k] = (__bf16)(v[k] * inv);
        #pragma unroll
        for (int k = 13; k < 32; k++) T2N[idx*32 + k] = (__bf16)0.0f;
    }
}

// ---------------------------------------------------------------------------
// fused MLP: 128 rows/block, 8 waves = (mt 0..3) x (ng 0..1), grid 512.
// LDS 152KB (1 block/CU):
//   xt  @0      [128][32]  bf16   8KB  (dead after L1)
//   h1  @8192   [128][320] bf16  80KB  (dead after af-cache)
//   h2c @90112  2x[128][128] bf16 64KB (chunk double-buffer)
//   h3  @8192   [128][128] bf16  32KB  (aliases h1)
//   t1s @40960  [128][17]  f32  8.5KB  (aliases h1)
// ---------------------------------------------------------------------------
__global__ __launch_bounds__(512) void mlp_kernel(const float* __restrict__ mem,
                                                  char* __restrict__ ws) {
    __shared__ char smem[155648];
    __bf16* xt  = (__bf16*)(smem);
    __bf16* h1  = (__bf16*)(smem + 8192);
    __bf16* h2c = (__bf16*)(smem + 90112);
    __bf16* h3  = (__bf16*)(smem + 8192);
    float*  t1s = (float*)(smem + 40960);

    const __bf16* W1B = (const __bf16*)(ws + OFF_W1B);
    const __bf16* W2B = (const __bf16*)(ws + OFF_W2B);
    const __bf16* W3B = (const __bf16*)(ws + OFF_W3B);
    const __bf16* W4B = (const __bf16*)(ws + OFF_W4B);
    const float*  B1  = (const float*)(ws + OFF_B1);
    const float*  B2  = (const float*)(ws + OFF_B2);
    const float*  B3  = (const float*)(ws + OFF_B3);
    const float*  B4  = (const float*)(ws + OFF_B4);
    __bf16* T1N = (__bf16*)(ws + OFF_T1N);

    const int tid = threadIdx.x;
    const int wave = tid >> 6, lane = tid & 63;
    const int lr = lane & 15, lg = lane >> 4;
    const int l31 = lane & 31, l5 = lane >> 5;
    const int mt = wave >> 1, ng = wave & 1;
    const int arow = mt*32 + l31;
    const int bm0 = blockIdx.x * 128;

    // stage x tile (zero-pad k 13..31)
    for (int i = tid; i < 128*32; i += 512) xt[i] = (__bf16)0.0f;
    __syncthreads();
    for (int i = tid; i < 128*13; i += 512) {
        int r = i / 13, c = i - r*13;
        xt[r*32 + swcol<3>(r, c)] = (__bf16)mem[(bm0 + r)*13 + c];
    }
    __syncthreads();

    // ---- L1 (32x32, frag-order weights): 5 n-tiles per wave ----
    {
        bf16x8 a0 = ld8(xt + arow*32 + ((l5 ^ (arow & 3)) << 3));
        bf16x8 a1 = ld8(xt + arow*32 + (((2 + l5) ^ (arow & 3)) << 3));
        f32x16 acc[5] = {};
        #pragma unroll
        for (int j = 0; j < 5; j++) {
            const int nt = ng*5 + j;
            bf16x8 b0 = ld8(W1B + ((nt*2 + 0)*64 + lane)*8);
            bf16x8 b1 = ld8(W1B + ((nt*2 + 1)*64 + lane)*8);
            acc[j] = mfma32(a0, b0, acc[j]);
            acc[j] = mfma32(a1, b1, acc[j]);
        }
        #pragma unroll
        for (int j = 0; j < 5; j++) {
            const int col = (ng*5 + j)*32 + l31;
            const float bb = B1[col];
            #pragma unroll
            for (int reg = 0; reg < 16; reg++) {
                const int rl = mt*32 + (reg & 3) + 8*(reg >> 2) + 4*l5;
                float v = acc[j][reg] + bb;
                v = v > 0.0f ? v : 0.0f;
                h1[rl*320 + swcol<7>(rl, col)] = (__bf16)v;
            }
        }
    }
    __syncthreads();

    // ---- af register cache: this wave's h1 row fragments (once!) ----
    bf16x8 afc[20];
    #pragma unroll
    for (int ks = 0; ks < 20; ks++)
        afc[ks] = ld8(h1 + arow*320 + (((2*ks + l5) ^ (arow & 7)) << 3));

    // ---- fused L2+L3, 5 chunks of 128 h2-cols ----
    f32x16 acc3a = {}, acc3b = {};

    auto l2chunk = [&](int c, int buf) {
        __bf16* dst = h2c + buf*16384;
        #pragma unroll
        for (int nt2 = 0; nt2 < 2; nt2++) {
            const int nt = c*4 + ng*2 + nt2;        // global n-tile 0..19
            const __bf16* bp = W2B + ((size_t)(nt*20)*64 + lane)*8;
            f32x16 e0 = {}, e1 = {};
            #pragma unroll
            for (int ks = 0; ks < 20; ks += 2) {
                e0 = mfma32(afc[ks],     ld8(bp + ks*512), e0);
                e1 = mfma32(afc[ks + 1], ld8(bp + ks*512 + 512), e1);
            }
            const int colc = (ng*2 + nt2)*32 + l31; // col within chunk
            const float bb = B2[nt*32 + l31];
            #pragma unroll
            for (int reg = 0; reg < 16; reg++) {
                const int rl = mt*32 + (reg & 3) + 8*(reg >> 2) + 4*l5;
                float v = e0[reg] + e1[reg] + bb;
                v = v > 0.0f ? v : 0.01f*v;
                dst[rl*128 + swcol<15>(rl, colc)] = (__bf16)v;
            }
        }
    };
    auto l3chunk = [&](int c) {
        const __bf16* src = h2c + (c & 1)*16384 + arow*128;
        const __bf16* bp0 = W3B + (((ng*2 + 0)*40 + c*8)*64 + (size_t)lane)*8;
        const __bf16* bp1 = W3B + (((ng*2 + 1)*40 + c*8)*64 + (size_t)lane)*8;
        #pragma unroll
        for (int ks = 0; ks < 8; ks++) {
            bf16x8 af = ld8(src + (((2*ks + l5) ^ (arow & 15)) << 3));
            acc3a = mfma32(af, ld8(bp0 + ks*512), acc3a);
            acc3b = mfma32(af, ld8(bp1 + ks*512), acc3b);
        }
    };

    l2chunk(0, 0);
    __syncthreads();
    for (int c = 0; c < 5; c++) {
        l3chunk(c);
        if (c < 4) l2chunk(c + 1, (c + 1) & 1);
        __syncthreads();
    }

    // L3 epilogue: bias+relu -> h3 (aliases h1; h1 dead since af-cache)
    {
        #pragma unroll
        for (int j = 0; j < 2; j++) {
            const int col = (ng*2 + j)*32 + l31;
            const float bb = B3[col];
            const f32x16& a = j ? acc3b : acc3a;
            #pragma unroll
            for (int reg = 0; reg < 16; reg++) {
                const int rl = mt*32 + (reg & 3) + 8*(reg >> 2) + 4*l5;
                float v = a[reg] + bb;
                v = v > 0.0f ? v : 0.0f;
                h3[rl*128 + swcol<15>(rl, col)] = (__bf16)v;
            }
        }
    }
    __syncthreads();

    // L4: 16 valid cols; 8 waves x one 16-row m-tile (16x16 path)
    {
        f32x4 a4 = {0.0f, 0.0f, 0.0f, 0.0f};
        const int ar = wave*16 + lr;
        #pragma unroll
        for (int ks = 0; ks < 4; ks++) {
            const int k0 = ks*32 + lg*8;
            bf16x8 bfv = ld8(W4B + lr*128 + k0);
            bf16x8 af = ld8(h3 + ar*128 + ((((k0 >> 3)) ^ (ar & 15)) << 3));
            a4 = mfma16(af, bfv, a4);
        }
        #pragma unroll
        for (int r = 0; r < 4; r++) {
            const int row = wave*16 + lg*4 + r;
            float v = a4[r] + B4[lr];
            v = v > 0.0f ? v : 0.01f*v;
            t1s[row*17 + lr] = v;
        }
    }
    __syncthreads();

    // normalize rows -> T1N [32]-padded bf16
    if (tid < 128) {
        float s = 0.0f, v[13];
        #pragma unroll
        for (int k = 0; k < 13; k++) { v[k] = t1s[tid*17 + k]; s += v[k]*v[k]; }
        const float inv = 1.0f / fmaxf(sqrtf(s), 1e-8f);
        __bf16 o[32];
        #pragma unroll
        for (int k = 0; k < 13; k++) o[k] = (__bf16)(v[k] * inv);
        #pragma unroll
        for (int k = 13; k < 32; k++) o[k] = (__bf16)0.0f;
        bf16x8* dst = reinterpret_cast<bf16x8*>(T1N + (size_t)(bm0 + tid)*32);
        const bf16x8* src = reinterpret_cast<const bf16x8*>(o);
        #pragma unroll
        for (int i = 0; i < 4; i++) dst[i] = src[i];
    }
}

// ---------------------------------------------------------------------------
// sim: 32x32 tiles, 64-way m-split (grid 1024). Per step 2 m-tiles,
// running max via fmax(fmax) -> v_max3 fusion.
// ---------------------------------------------------------------------------
__global__ __launch_bounds__(256) void sim_kernel(const char* __restrict__ ws_c,
                                                  float* __restrict__ part) {
    const char* ws = ws_c;
    const __bf16* T1N = (const __bf16*)(ws + OFF_T1N);
    const __bf16* T2N = (const __bf16*)(ws + OFF_T2N);
    const int wave = threadIdx.x >> 6, lane = threadIdx.x & 63;
    const int l31 = lane & 31, l5 = lane >> 5;
    const int bgroup = blockIdx.x & 15, ms = blockIdx.x >> 4;   // 16 x 64 grid
    const int b0 = (bgroup*4 + wave) * 32;

    const bf16x8 af0 = ld8(T2N + (b0 + l31)*32 + l5*8);
    const bf16x8 af1 = ld8(T2N + (b0 + l31)*32 + 16 + l5*8);
    const f32x16 zero = {};
    f32x16 mx;
    #pragma unroll
    for (int r = 0; r < 16; r++) mx[r] = -3.0e38f;

    #pragma unroll 4
    for (int mt = ms; mt < 2048; mt += 128) {
        const __bf16* p0 = T1N + ((size_t)mt*32 + l31)*32 + l5*8;
        const __bf16* p1 = T1N + ((size_t)(mt + 64)*32 + l31)*32 + l5*8;
        bf16x8 b00 = ld8(p0);
        bf16x8 b01 = ld8(p0 + 16);
        bf16x8 b10 = ld8(p1);
        bf16x8 b11 = ld8(p1 + 16);
        f32x16 d0 = mfma32(af1, b01, mfma32(af0, b00, zero));
        f32x16 d1 = mfma32(af1, b11, mfma32(af0, b10, zero));
        #pragma unroll
        for (int r = 0; r < 16; r++)
            mx[r] = fmaxf(mx[r], fmaxf(d0[r], d1[r]));   // -> v_max3_f32
    }
    #pragma unroll
    for (int off = 1; off <= 16; off <<= 1) {
        #pragma unroll
        for (int r = 0; r < 16; r++) mx[r] = fmaxf(mx[r], __shfl_xor(mx[r], off));
    }
    if (l31 == 0) {
        #pragma unroll
        for (int reg = 0; reg < 16; reg++)
            part[ms*2048 + b0 + (reg & 3) + 8*(reg >> 2) + 4*l5] = mx[reg];
    }
}

__global__ void reduce_kernel(const float* __restrict__ part, float* __restrict__ out) {
    int b = blockIdx.x*256 + threadIdx.x;
    if (b < 2048) {
        float m = part[b];
        #pragma unroll
        for (int ms = 1; ms < 64; ms++) m = fmaxf(m, part[ms*2048 + b]);
        out[b] = 23.0f * m;
    }
}

// ---------------------------------------------------------------------------
extern "C" void kernel_launch(void* const* d_in, const int* in_sizes, int n_in,
                              void* d_out, int out_size, void* d_ws, size_t ws_size,
                              hipStream_t stream) {
    const float* memory = (const float*)d_in[0];
    const float* value  = (const float*)d_in[1];
    const float* W1 = (const float*)d_in[2]; const float* b1 = (const float*)d_in[3];
    const float* W2 = (const float*)d_in[4]; const float* b2 = (const float*)d_in[5];
    const float* W3 = (const float*)d_in[6]; const float* b3 = (const float*)d_in[7];
    const float* W4 = (const float*)d_in[8]; const float* b4 = (const float*)d_in[9];
    char* ws = (char*)d_ws;
    float* part = (float*)(ws + OFF_PART);
    float* out = (float*)d_out;

    prep_kernel<<<1189, 256, 0, stream>>>(W1, b1, W2, b2, W3, b3, W4, b4, value, ws);
    mlp_kernel<<<512, 512, 0, stream>>>(memory, ws);
    sim_kernel<<<1024, 256, 0, stream>>>(ws, part);
    reduce_kernel<<<8, 256, 0, stream>>>(part, out);
}

// Round 7
// 132.436 us; speedup vs baseline: 1.5125x; 1.5125x over previous
//
#include <hip/hip_runtime.h>

// ---------------------------------------------------------------------------
// memory_tree R7: all-register MLP via swapped-operand MFMA.
// Every layer computes D[n][m] = W x act^T (A=W frag-order, B=activation
// frags, lane&31 = m). cvt_pk_bf16 + permlane32_swap converts each f32x16
// accumulator directly into the next layer's B-fragments -- activations
// never touch LDS/HBM. Biases folded in as an extra k-channel (act=1.0).
// Only weights stream LDS (28KB/nt2, double-buffered, reg-staged T14-style).
// Wave owns 32 rows; block = 8 waves = 256 rows; grid 256 (1 block/CU).
// ---------------------------------------------------------------------------

typedef __bf16 bf16x8 __attribute__((ext_vector_type(8)));
typedef float f32x16 __attribute__((ext_vector_type(16)));

// ---- workspace layout (bytes) ---------------------------------------------
constexpr size_t OFF_W1B = 0;                    // [10 nt][64][8] bf16 = 10240
constexpr size_t OFF_W2B = 10240;                // [20 nt][20 ks][64][8] = 409600
constexpr size_t OFF_W3B = 419840;               // [4 nt][40 ks][64][8] = 163840
constexpr size_t OFF_W4B = 583680;               // [8 ks][64][8] = 8192
constexpr size_t OFF_T2N = 591872;               // [2048][32] bf16 = 131072
constexpr size_t OFF_T1N = 722944;               // [65536][32] bf16 = 4194304
constexpr size_t OFF_PART= 4917248;              // [64][2048] f32 = 524288
// total: 5441536 bytes

__device__ __forceinline__ bf16x8 ld8(const __bf16* p) {
    return *reinterpret_cast<const bf16x8*>(p);
}
__device__ __forceinline__ f32x16 mfma32(bf16x8 a, bf16x8 b, f32x16 c) {
    return __builtin_amdgcn_mfma_f32_32x32x16_bf16(a, b, c, 0, 0, 0);
}

// Convert D-layout f32x16 (col=lane&31, row n=(reg&3)+8*(reg>>2)+4*hi) into
// two K=16 B-fragments (lane&31 = col, k = hi*8+e) covering n 0..15 / 16..31.
// Verified lane algebra: f0 = [S02.r0, S13.r0, S02.r1, S13.r1],
//                        f1 = [S46.r0, S57.r0, S46.r1, S57.r1]
// where Sxy = permlane32_swap(Wx, Wy), Wj = cvt_pk(a[2j], a[2j+1]).
__device__ __forceinline__ void cvtswap(const f32x16& a, bf16x8& f0, bf16x8& f1) {
    unsigned w[8];
    #pragma unroll
    for (int j = 0; j < 8; j++)
        asm("v_cvt_pk_bf16_f32 %0, %1, %2" : "=v"(w[j]) : "v"(a[2*j]), "v"(a[2*j+1]));
    unsigned a0 = w[0], b0 = w[2]; asm("v_permlane32_swap_b32 %0, %1" : "+v"(a0), "+v"(b0));
    unsigned a1 = w[1], b1 = w[3]; asm("v_permlane32_swap_b32 %0, %1" : "+v"(a1), "+v"(b1));
    unsigned a2 = w[4], b2 = w[6]; asm("v_permlane32_swap_b32 %0, %1" : "+v"(a2), "+v"(b2));
    unsigned a3 = w[5], b3 = w[7]; asm("v_permlane32_swap_b32 %0, %1" : "+v"(a3), "+v"(b3));
    union { unsigned u[4]; bf16x8 v; } p, q;
    p.u[0] = a0; p.u[1] = a1; p.u[2] = b0; p.u[3] = b1; f0 = p.v;
    q.u[0] = a2; q.u[1] = a3; q.u[2] = b2; q.u[3] = b3; f1 = q.v;
}

// ---------------------------------------------------------------------------
// prep: weights -> bf16 frag-order with bias-as-k-channel; t2n normalize
// ---------------------------------------------------------------------------
__global__ void prep_kernel(const float* __restrict__ W1, const float* __restrict__ b1,
                            const float* __restrict__ W2, const float* __restrict__ b2,
                            const float* __restrict__ W3, const float* __restrict__ b3,
                            const float* __restrict__ W4, const float* __restrict__ b4,
                            const float* __restrict__ value, char* __restrict__ ws) {
    __bf16* W1B = (__bf16*)(ws + OFF_W1B);
    __bf16* W2B = (__bf16*)(ws + OFF_W2B);
    __bf16* W3B = (__bf16*)(ws + OFF_W3B);
    __bf16* W4B = (__bf16*)(ws + OFF_W4B);
    __bf16* T2N = (__bf16*)(ws + OFF_T2N);

    int idx = blockIdx.x * 256 + threadIdx.x;
    if (idx < 5120) {                        // W1B [nt<10][64][8]; k-dim 16 (13 data + bias@13)
        int e = idx & 7, lane = (idx >> 3) & 63, nt = idx >> 9;
        int n = nt*32 + (lane & 31);
        int k = (lane >> 5)*8 + e;
        float v = 0.0f;
        if (n < 300)      v = (k < 13) ? W1[n*13 + k] : (k == 13 ? b1[n] : 0.0f);
        else if (n == 300) v = (k == 13) ? 1.0f : 0.0f;    // h1 bias channel
        W1B[idx] = (__bf16)v;
        return;
    }
    idx -= 5120;
    if (idx < 204800) {                      // W2B [nt<20][ks<20][64][8]; k 320 (300+bias@300)
        int e = idx & 7, lane = (idx >> 3) & 63, r = idx >> 9;
        int ks = r % 20, nt = r / 20;
        int n = nt*32 + (lane & 31);
        int k = ks*16 + (lane >> 5)*8 + e;
        float v = 0.0f;
        if (n < 600)      v = (k < 300) ? W2[n*300 + k] : (k == 300 ? b2[n] : 0.0f);
        else if (n == 600) v = (k == 300) ? 1.0f : 0.0f;   // h2 bias channel
        W2B[idx] = (__bf16)v;
        return;
    }
    idx -= 204800;
    if (idx < 81920) {                       // W3B [nt<4][ks<40][64][8]; k 640 (600+bias@600)
        int e = idx & 7, lane = (idx >> 3) & 63, r = idx >> 9;
        int ks = r % 40, nt = r / 40;
        int n = nt*32 + (lane & 31);
        int k = ks*16 + (lane >> 5)*8 + e;
        float v = 0.0f;
        if (n < 100)      v = (k < 600) ? W3[n*600 + k] : (k == 600 ? b3[n] : 0.0f);
        else if (n == 100) v = (k == 600) ? 1.0f : 0.0f;   // h3 bias channel
        W3B[idx] = (__bf16)v;
        return;
    }
    idx -= 81920;
    if (idx < 4096) {                        // W4B [ks<8][64][8]; k 128 (100+bias@100)
        int e = idx & 7, lane = (idx >> 3) & 63, ks = idx >> 9;
        int n = lane & 31;
        int k = ks*16 + (lane >> 5)*8 + e;
        float v = 0.0f;
        if (n < 13) v = (k < 100) ? W4[n*100 + k] : (k == 100 ? b4[n] : 0.0f);
        W4B[idx] = (__bf16)v;                // rows 13..31 zero -> exact-0 pads
        return;
    }
    idx -= 4096;
    if (idx < 2048) {                        // t2n rows
        float v[13]; float s = 0.0f;
        #pragma unroll
        for (int k = 0; k < 13; k++) { v[k] = value[idx*13 + k]; s += v[k]*v[k]; }
        float inv = 1.0f / fmaxf(sqrtf(s), 1e-8f);
        #pragma unroll
        for (int k = 0; k < 13; k++) T2N[idx*32 + k] = (__bf16)(v[k] * inv);
        #pragma unroll
        for (int k = 13; k < 32; k++) T2N[idx*32 + k] = (__bf16)0.0f;
    }
}

// ---------------------------------------------------------------------------
// mlp: 256 rows/block, 8 waves (wave owns rows wave*32..+31, lane&31 = row).
// LDS: 2 x 28KB weight stage (blocks 0..19 = W2[nt2][ks], 20..27 = W3 frags
// for this nt2) + t1s [256][13] f32.  All activations in registers.
// ---------------------------------------------------------------------------
__global__ __launch_bounds__(512, 1) void mlp_kernel(const float* __restrict__ mem,
                                                     char* __restrict__ ws) {
    __shared__ char smem[70656];
    __bf16* stg = (__bf16*)smem;              // 2 x 14336 elems (28KB each)
    float*  t1s = (float*)(smem + 57344);     // [256][13]

    const __bf16* W1B = (const __bf16*)(ws + OFF_W1B);
    const __bf16* W2B = (const __bf16*)(ws + OFF_W2B);
    const __bf16* W3B = (const __bf16*)(ws + OFF_W3B);
    const __bf16* W4B = (const __bf16*)(ws + OFF_W4B);
    __bf16* T1N = (__bf16*)(ws + OFF_T1N);

    const int tid = threadIdx.x;
    const int wave = tid >> 6, lane = tid & 63;
    const int l31 = lane & 31, hi = lane >> 5;
    const int bm0 = blockIdx.x * 256;
    const int m = bm0 + wave*32 + l31;        // this lane's memory row

    // helper: global source for stage block blk at step nt2
    auto src_of = [&](int nt2, int blk) -> const __bf16* {
        return (blk < 20)
            ? W2B + (size_t)(nt2*20 + blk)*512
            : W3B + (size_t)((((blk-20)>>1)*40) + 2*nt2 + ((blk-20)&1))*512;
    };

    // ---- prologue stage(nt2=0) loads (hide under x-load + L1) ----
    bf16x8 sreg[4];
    #pragma unroll
    for (int i = 0; i < 4; i++) {
        const int blk = wave + i*8;
        if (blk < 28) sreg[i] = ld8(src_of(0, blk) + lane*8);
    }

    // ---- x B-fragment (k = hi*8+e; bias channel 1.0 at k=13) ----
    bf16x8 xf;
    {
        union { __bf16 h[8]; bf16x8 v; } u;
        const float* xr = mem + (size_t)m*13;
        if (hi == 0) {
            #pragma unroll
            for (int e = 0; e < 8; e++) u.h[e] = (__bf16)xr[e];
        } else {
            #pragma unroll
            for (int e = 0; e < 5; e++) u.h[e] = (__bf16)xr[8 + e];
            u.h[5] = (__bf16)1.0f;   // k=13 bias channel
            u.h[6] = (__bf16)0.0f;
            u.h[7] = (__bf16)0.0f;
        }
        xf = u.v;
    }

    // ---- L1: 10 n-tiles, one K=16 MFMA each -> afc[20] h1 B-fragments ----
    bf16x8 afc[20];
    #pragma unroll
    for (int nt = 0; nt < 10; nt++) {
        bf16x8 wf = ld8(W1B + (size_t)nt*512 + lane*8);
        f32x16 z = {};
        f32x16 a = mfma32(wf, xf, z);
        #pragma unroll
        for (int r = 0; r < 16; r++) a[r] = fmaxf(a[r], 0.0f);   // relu
        cvtswap(a, afc[2*nt], afc[2*nt + 1]);
    }

    // ---- write prologue stage, barrier ----
    #pragma unroll
    for (int i = 0; i < 4; i++) {
        const int blk = wave + i*8;
        if (blk < 28) *reinterpret_cast<bf16x8*>(stg + blk*512 + lane*8) = sreg[i];
    }
    __syncthreads();

    // ---- fused L2+L3 over 20 n2-tiles; weights from staged LDS ----
    f32x16 acc3[4] = {};
    int buf = 0;
    for (int nt2 = 0; nt2 < 20; nt2++) {
        // issue next-step global loads early (T14: issue-early / write-late)
        if (nt2 < 19) {
            #pragma unroll
            for (int i = 0; i < 4; i++) {
                const int blk = wave + i*8;
                if (blk < 28) sreg[i] = ld8(src_of(nt2 + 1, blk) + lane*8);
            }
        }
        const __bf16* sb = stg + buf*14336;
        // L2: acc2 = W2[nt2] x h1 (2-chain ILP)
        f32x16 e0 = {}, e1 = {};
        #pragma unroll
        for (int ks = 0; ks < 20; ks += 2) {
            e0 = mfma32(ld8(sb + ks*512 + lane*8),       afc[ks],     e0);
            e1 = mfma32(ld8(sb + (ks + 1)*512 + lane*8), afc[ks + 1], e1);
        }
        // leaky + convert to h2 fragments (in-place into e0)
        #pragma unroll
        for (int r = 0; r < 16; r++) {
            float v = e0[r] + e1[r];
            e0[r] = fmaxf(v, 0.0f) + 0.01f*fminf(v, 0.0f);
        }
        bf16x8 h2f0, h2f1;
        cvtswap(e0, h2f0, h2f1);
        // L3: accumulate into persistent acc3[4]
        #pragma unroll
        for (int n3 = 0; n3 < 4; n3++) {
            acc3[n3] = mfma32(ld8(sb + (20 + 2*n3)*512 + lane*8), h2f0, acc3[n3]);
            acc3[n3] = mfma32(ld8(sb + (21 + 2*n3)*512 + lane*8), h2f1, acc3[n3]);
        }
        // write next stage late, then barrier
        if (nt2 < 19) {
            #pragma unroll
            for (int i = 0; i < 4; i++) {
                const int blk = wave + i*8;
                if (blk < 28)
                    *reinterpret_cast<bf16x8*>(stg + (buf^1)*14336 + blk*512 + lane*8) = sreg[i];
            }
        }
        __syncthreads();
        buf ^= 1;
    }

    // ---- L3 relu + convert -> L4 (W4 frags direct from global) ----
    f32x16 acc4 = {};
    #pragma unroll
    for (int n3 = 0; n3 < 4; n3++) {
        f32x16 h;
        #pragma unroll
        for (int r = 0; r < 16; r++) h[r] = fmaxf(acc3[n3][r], 0.0f);
        bf16x8 f0, f1;
        cvtswap(h, f0, f1);
        acc4 = mfma32(ld8(W4B + (size_t)(2*n3)*512 + lane*8),     f0, acc4);
        acc4 = mfma32(ld8(W4B + (size_t)(2*n3 + 1)*512 + lane*8), f1, acc4);
    }
    // leaky + scatter valid t1 values to LDS (pads are exact 0, skipped)
    const int mrow = wave*32 + l31;
    #pragma unroll
    for (int r = 0; r < 16; r++) {
        const int n4 = (r & 3) + 8*(r >> 2) + 4*hi;
        if (n4 < 13) {
            float v = acc4[r];
            t1s[mrow*13 + n4] = fmaxf(v, 0.0f) + 0.01f*fminf(v, 0.0f);
        }
    }
    __syncthreads();

    // ---- normalize rows -> T1N [32]-padded bf16 (coalesced 64B/thread) ----
    if (tid < 256) {
        float s = 0.0f, v[13];
        #pragma unroll
        for (int k = 0; k < 13; k++) { v[k] = t1s[tid*13 + k]; s += v[k]*v[k]; }
        const float inv = 1.0f / fmaxf(sqrtf(s), 1e-8f);
        __bf16 o[32];
        #pragma unroll
        for (int k = 0; k < 13; k++) o[k] = (__bf16)(v[k] * inv);
        #pragma unroll
        for (int k = 13; k < 32; k++) o[k] = (__bf16)0.0f;
        bf16x8* dst = reinterpret_cast<bf16x8*>(T1N + (size_t)(bm0 + tid)*32);
        const bf16x8* src = reinterpret_cast<const bf16x8*>(o);
        #pragma unroll
        for (int i = 0; i < 4; i++) dst[i] = src[i];
    }
}

// ---------------------------------------------------------------------------
// sim: 32x32 tiles, 64-way m-split (grid 1024). Per step 2 m-tiles,
// running max via fmax(fmax) -> v_max3 fusion.
// ---------------------------------------------------------------------------
__global__ __launch_bounds__(256) void sim_kernel(const char* __restrict__ ws_c,
                                                  float* __restrict__ part) {
    const char* ws = ws_c;
    const __bf16* T1N = (const __bf16*)(ws + OFF_T1N);
    const __bf16* T2N = (const __bf16*)(ws + OFF_T2N);
    const int wave = threadIdx.x >> 6, lane = threadIdx.x & 63;
    const int l31 = lane & 31, l5 = lane >> 5;
    const int bgroup = blockIdx.x & 15, ms = blockIdx.x >> 4;   // 16 x 64 grid
    const int b0 = (bgroup*4 + wave) * 32;

    const bf16x8 af0 = ld8(T2N + (b0 + l31)*32 + l5*8);
    const bf16x8 af1 = ld8(T2N + (b0 + l31)*32 + 16 + l5*8);
    const f32x16 zero = {};
    f32x16 mx;
    #pragma unroll
    for (int r = 0; r < 16; r++) mx[r] = -3.0e38f;

    #pragma unroll 4
    for (int mt = ms; mt < 2048; mt += 128) {
        const __bf16* p0 = T1N + ((size_t)mt*32 + l31)*32 + l5*8;
        const __bf16* p1 = T1N + ((size_t)(mt + 64)*32 + l31)*32 + l5*8;
        bf16x8 b00 = ld8(p0);
        bf16x8 b01 = ld8(p0 + 16);
        bf16x8 b10 = ld8(p1);
        bf16x8 b11 = ld8(p1 + 16);
        f32x16 d0 = mfma32(af1, b01, mfma32(af0, b00, zero));
        f32x16 d1 = mfma32(af1, b11, mfma32(af0, b10, zero));
        #pragma unroll
        for (int r = 0; r < 16; r++)
            mx[r] = fmaxf(mx[r], fmaxf(d0[r], d1[r]));
    }
    #pragma unroll
    for (int off = 1; off <= 16; off <<= 1) {
        #pragma unroll
        for (int r = 0; r < 16; r++) mx[r] = fmaxf(mx[r], __shfl_xor(mx[r], off));
    }
    if (l31 == 0) {
        #pragma unroll
        for (int reg = 0; reg < 16; reg++)
            part[ms*2048 + b0 + (reg & 3) + 8*(reg >> 2) + 4*l5] = mx[reg];
    }
}

__global__ void reduce_kernel(const float* __restrict__ part, float* __restrict__ out) {
    int b = blockIdx.x*256 + threadIdx.x;
    if (b < 2048) {
        float m = part[b];
        #pragma unroll
        for (int ms = 1; ms < 64; ms++) m = fmaxf(m, part[ms*2048 + b]);
        out[b] = 23.0f * m;
    }
}

// ---------------------------------------------------------------------------
extern "C" void kernel_launch(void* const* d_in, const int* in_sizes, int n_in,
                              void* d_out, int out_size, void* d_ws, size_t ws_size,
                              hipStream_t stream) {
    const float* memory = (const float*)d_in[0];
    const float* value  = (const float*)d_in[1];
    const float* W1 = (const float*)d_in[2]; const float* b1 = (const float*)d_in[3];
    const float* W2 = (const float*)d_in[4]; const float* b2 = (const float*)d_in[5];
    const float* W3 = (const float*)d_in[6]; const float* b3 = (const float*)d_in[7];
    const float* W4 = (const float*)d_in[8]; const float* b4 = (const float*)d_in[9];
    char* ws = (char*)d_ws;
    float* part = (float*)(ws + OFF_PART);
    float* out = (float*)d_out;

    prep_kernel<<<1164, 256, 0, stream>>>(W1, b1, W2, b2, W3, b3, W4, b4, value, ws);
    mlp_kernel<<<256, 512, 0, stream>>>(memory, ws);
    sim_kernel<<<1024, 256, 0, stream>>>(ws, part);
    reduce_kernel<<<8, 256, 0, stream>>>(part, out);
}

// Round 8
// 124.944 us; speedup vs baseline: 1.6031x; 1.0600x over previous
//
#include <hip/hip_runtime.h>

// ---------------------------------------------------------------------------
// memory_tree R8: all-register MLP (swapped-operand MFMA, cvt_pk+permlane
// inter-layer) + K=16 sim.
// - t1n/t2n padded to 16 (not 32): one 32x32x16 MFMA per sim tile, T1N=2MB
//   (L2-resident/XCD), sim traffic halved.
// - mlp: BM=128, 4 waves, grid 512, 2 blocks/CU (LDS 46.5KB). Only W2 staged
//   in LDS (20KB dbuf, T14 issue-early/write-late); W3 direct from L2.
// - launch_bounds 2nd arg = CUDA-style min-blocks/CU on this toolchain
//   (R4/R5 evidence): (256,2) -> 2 blk/CU, VGPR cap 256, no spill at ~246.
// ---------------------------------------------------------------------------

typedef __bf16 bf16x8 __attribute__((ext_vector_type(8)));
typedef float f32x16 __attribute__((ext_vector_type(16)));

// ---- workspace layout (bytes) ---------------------------------------------
constexpr size_t OFF_W1B = 0;                    // [10 nt][64][8] bf16 = 10240
constexpr size_t OFF_W2B = 10240;                // [20 nt][20 ks][64][8] = 409600
constexpr size_t OFF_W3B = 419840;               // [4 nt][40 ks][64][8] = 163840
constexpr size_t OFF_W4B = 583680;               // [8 ks][64][8] = 8192
constexpr size_t OFF_T2N = 591872;               // [2048][16] bf16 = 65536
constexpr size_t OFF_T1N = 657408;               // [65536][16] bf16 = 2097152
constexpr size_t OFF_PART= 2754560;              // [64][2048] f32 = 524288
// total: 3278848 bytes (~3.3 MB)

__device__ __forceinline__ bf16x8 ld8(const __bf16* p) {
    return *reinterpret_cast<const bf16x8*>(p);
}
__device__ __forceinline__ f32x16 mfma32(bf16x8 a, bf16x8 b, f32x16 c) {
    return __builtin_amdgcn_mfma_f32_32x32x16_bf16(a, b, c, 0, 0, 0);
}

// Convert D-layout f32x16 (col=lane&31, row n=(reg&3)+8*(reg>>2)+4*hi) into
// two K=16 B-fragments (lane&31 = col, k = hi*8+e) covering n 0..15 / 16..31.
// f0 = [S02.r0, S13.r0, S02.r1, S13.r1], f1 = [S46.r0, S57.r0, S46.r1, S57.r1]
// where Sxy = permlane32_swap(Wx, Wy), Wj = cvt_pk(a[2j], a[2j+1]).
__device__ __forceinline__ void cvtswap(const f32x16& a, bf16x8& f0, bf16x8& f1) {
    unsigned w[8];
    #pragma unroll
    for (int j = 0; j < 8; j++)
        asm("v_cvt_pk_bf16_f32 %0, %1, %2" : "=v"(w[j]) : "v"(a[2*j]), "v"(a[2*j+1]));
    unsigned a0 = w[0], b0 = w[2]; asm("v_permlane32_swap_b32 %0, %1" : "+v"(a0), "+v"(b0));
    unsigned a1 = w[1], b1 = w[3]; asm("v_permlane32_swap_b32 %0, %1" : "+v"(a1), "+v"(b1));
    unsigned a2 = w[4], b2 = w[6]; asm("v_permlane32_swap_b32 %0, %1" : "+v"(a2), "+v"(b2));
    unsigned a3 = w[5], b3 = w[7]; asm("v_permlane32_swap_b32 %0, %1" : "+v"(a3), "+v"(b3));
    union { unsigned u[4]; bf16x8 v; } p, q;
    p.u[0] = a0; p.u[1] = a1; p.u[2] = b0; p.u[3] = b1; f0 = p.v;
    q.u[0] = a2; q.u[1] = a3; q.u[2] = b2; q.u[3] = b3; f1 = q.v;
}

// ---------------------------------------------------------------------------
// prep: weights -> bf16 frag-order with bias-as-k-channel; t2n normalize
// ---------------------------------------------------------------------------
__global__ void prep_kernel(const float* __restrict__ W1, const float* __restrict__ b1,
                            const float* __restrict__ W2, const float* __restrict__ b2,
                            const float* __restrict__ W3, const float* __restrict__ b3,
                            const float* __restrict__ W4, const float* __restrict__ b4,
                            const float* __restrict__ value, char* __restrict__ ws) {
    __bf16* W1B = (__bf16*)(ws + OFF_W1B);
    __bf16* W2B = (__bf16*)(ws + OFF_W2B);
    __bf16* W3B = (__bf16*)(ws + OFF_W3B);
    __bf16* W4B = (__bf16*)(ws + OFF_W4B);
    __bf16* T2N = (__bf16*)(ws + OFF_T2N);

    int idx = blockIdx.x * 256 + threadIdx.x;
    if (idx < 5120) {                        // W1B [nt<10][64][8]; k 16 (13 + bias@13)
        int e = idx & 7, lane = (idx >> 3) & 63, nt = idx >> 9;
        int n = nt*32 + (lane & 31);
        int k = (lane >> 5)*8 + e;
        float v = 0.0f;
        if (n < 300)       v = (k < 13) ? W1[n*13 + k] : (k == 13 ? b1[n] : 0.0f);
        else if (n == 300) v = (k == 13) ? 1.0f : 0.0f;    // h1 bias channel
        W1B[idx] = (__bf16)v;
        return;
    }
    idx -= 5120;
    if (idx < 204800) {                      // W2B [nt<20][ks<20][64][8]; k 320 (300+bias)
        int e = idx & 7, lane = (idx >> 3) & 63, r = idx >> 9;
        int ks = r % 20, nt = r / 20;
        int n = nt*32 + (lane & 31);
        int k = ks*16 + (lane >> 5)*8 + e;
        float v = 0.0f;
        if (n < 600)       v = (k < 300) ? W2[n*300 + k] : (k == 300 ? b2[n] : 0.0f);
        else if (n == 600) v = (k == 300) ? 1.0f : 0.0f;   // h2 bias channel
        W2B[idx] = (__bf16)v;
        return;
    }
    idx -= 204800;
    if (idx < 81920) {                       // W3B [nt<4][ks<40][64][8]; k 640 (600+bias)
        int e = idx & 7, lane = (idx >> 3) & 63, r = idx >> 9;
        int ks = r % 40, nt = r / 40;
        int n = nt*32 + (lane & 31);
        int k = ks*16 + (lane >> 5)*8 + e;
        float v = 0.0f;
        if (n < 100)       v = (k < 600) ? W3[n*600 + k] : (k == 600 ? b3[n] : 0.0f);
        else if (n == 100) v = (k == 600) ? 1.0f : 0.0f;   // h3 bias channel
        W3B[idx] = (__bf16)v;
        return;
    }
    idx -= 81920;
    if (idx < 4096) {                        // W4B [ks<8][64][8]; k 128 (100+bias@100)
        int e = idx & 7, lane = (idx >> 3) & 63, ks = idx >> 9;
        int n = lane & 31;
        int k = ks*16 + (lane >> 5)*8 + e;
        float v = 0.0f;
        if (n < 13) v = (k < 100) ? W4[n*100 + k] : (k == 100 ? b4[n] : 0.0f);
        W4B[idx] = (__bf16)v;                // rows 13..31 zero -> exact-0 pads
        return;
    }
    idx -= 4096;
    if (idx < 2048) {                        // t2n rows ([16], k>=13 zero)
        float v[13]; float s = 0.0f;
        #pragma unroll
        for (int k = 0; k < 13; k++) { v[k] = value[idx*13 + k]; s += v[k]*v[k]; }
        float inv = 1.0f / fmaxf(sqrtf(s), 1e-8f);
        #pragma unroll
        for (int k = 0; k < 13; k++) T2N[idx*16 + k] = (__bf16)(v[k] * inv);
        #pragma unroll
        for (int k = 13; k < 16; k++) T2N[idx*16 + k] = (__bf16)0.0f;
    }
}

// ---------------------------------------------------------------------------
// mlp: 128 rows/block, 4 waves (wave owns rows wave*32..+31, lane&31 = row).
// grid 512 => 2 blocks/CU. LDS: 2 x 20KB W2 stage + t1s [128][13] f32.
// All activations in registers; W3/W4/W1 weights direct from L2.
// ---------------------------------------------------------------------------
__global__ __launch_bounds__(256, 2) void mlp_kernel(const float* __restrict__ mem,
                                                     char* __restrict__ ws) {
    __shared__ char smem[47616];
    __bf16* stg = (__bf16*)smem;              // 2 x 10240 elems (20KB each)
    float*  t1s = (float*)(smem + 40960);     // [128][13]

    const __bf16* W1B = (const __bf16*)(ws + OFF_W1B);
    const __bf16* W2B = (const __bf16*)(ws + OFF_W2B);
    const __bf16* W3B = (const __bf16*)(ws + OFF_W3B);
    const __bf16* W4B = (const __bf16*)(ws + OFF_W4B);
    __bf16* T1N = (__bf16*)(ws + OFF_T1N);

    const int tid = threadIdx.x;
    const int wave = tid >> 6, lane = tid & 63;
    const int l31 = lane & 31, hi = lane >> 5;
    const int bm0 = blockIdx.x * 128;
    const int m = bm0 + wave*32 + l31;        // this lane's memory row

    // ---- prologue: stage(nt2=0) loads (1280 slots, 5 per thread) ----
    bf16x8 sreg[5];
    #pragma unroll
    for (int i = 0; i < 5; i++)
        sreg[i] = ld8(W2B + (size_t)(tid + i*256)*8);

    // ---- x B-fragment (k = hi*8+e; bias channel 1.0 at k=13) ----
    bf16x8 xf;
    {
        union { __bf16 h[8]; bf16x8 v; } u;
        const float* xr = mem + (size_t)m*13;
        if (hi == 0) {
            #pragma unroll
            for (int e = 0; e < 8; e++) u.h[e] = (__bf16)xr[e];
        } else {
            #pragma unroll
            for (int e = 0; e < 5; e++) u.h[e] = (__bf16)xr[8 + e];
            u.h[5] = (__bf16)1.0f;   // k=13 bias channel
            u.h[6] = (__bf16)0.0f;
            u.h[7] = (__bf16)0.0f;
        }
        xf = u.v;
    }

    // ---- L1: 10 n-tiles, one K=16 MFMA each -> afc[20] h1 B-fragments ----
    bf16x8 afc[20];
    #pragma unroll
    for (int nt = 0; nt < 10; nt++) {
        bf16x8 wf = ld8(W1B + (size_t)nt*512 + lane*8);
        f32x16 z = {};
        f32x16 a = mfma32(wf, xf, z);
        #pragma unroll
        for (int r = 0; r < 16; r++) a[r] = fmaxf(a[r], 0.0f);   // relu
        cvtswap(a, afc[2*nt], afc[2*nt + 1]);
    }

    // ---- write prologue stage, barrier ----
    #pragma unroll
    for (int i = 0; i < 5; i++)
        *reinterpret_cast<bf16x8*>(stg + (tid + i*256)*8) = sreg[i];
    __syncthreads();

    // ---- fused L2+L3 over 20 n2-tiles; W2 from staged LDS, W3 direct ----
    f32x16 acc3[4] = {};
    int buf = 0;
    for (int nt2 = 0; nt2 < 20; nt2++) {
        // issue next-step W2 loads early (T14: issue-early / write-late)
        if (nt2 < 19) {
            #pragma unroll
            for (int i = 0; i < 5; i++)
                sreg[i] = ld8(W2B + (size_t)(nt2 + 1)*10240 + (size_t)(tid + i*256)*8);
        }
        const __bf16* sb = stg + buf*10240;
        // L2: acc2 = W2[nt2] x h1 (2-chain ILP, 20 ds_read_b128 + 20 MFMA)
        f32x16 e0 = {}, e1 = {};
        #pragma unroll
        for (int ks = 0; ks < 20; ks += 2) {
            e0 = mfma32(ld8(sb + ks*512 + lane*8),       afc[ks],     e0);
            e1 = mfma32(ld8(sb + (ks + 1)*512 + lane*8), afc[ks + 1], e1);
        }
        // leaky + convert to h2 fragments
        #pragma unroll
        for (int r = 0; r < 16; r++) {
            float v = e0[r] + e1[r];
            e0[r] = fmaxf(v, 0.0f) + 0.01f*fminf(v, 0.0f);
        }
        bf16x8 h2f0, h2f1;
        cvtswap(e0, h2f0, h2f1);
        // L3: 8 MFMAs, W3 frags straight from L2 (independent loads)
        #pragma unroll
        for (int n3 = 0; n3 < 4; n3++) {
            const __bf16* bp = W3B + ((size_t)(n3*40 + 2*nt2)*64 + lane)*8;
            acc3[n3] = mfma32(ld8(bp),       h2f0, acc3[n3]);
            acc3[n3] = mfma32(ld8(bp + 512), h2f1, acc3[n3]);
        }
        // write next stage late, then barrier
        if (nt2 < 19) {
            #pragma unroll
            for (int i = 0; i < 5; i++)
                *reinterpret_cast<bf16x8*>(stg + (buf^1)*10240 + (tid + i*256)*8) = sreg[i];
        }
        __syncthreads();
        buf ^= 1;
    }

    // ---- L3 relu + convert -> L4 (W4 frags direct from global) ----
    f32x16 acc4 = {};
    #pragma unroll
    for (int n3 = 0; n3 < 4; n3++) {
        f32x16 h;
        #pragma unroll
        for (int r = 0; r < 16; r++) h[r] = fmaxf(acc3[n3][r], 0.0f);
        bf16x8 f0, f1;
        cvtswap(h, f0, f1);
        acc4 = mfma32(ld8(W4B + (size_t)(2*n3)*512 + lane*8),     f0, acc4);
        acc4 = mfma32(ld8(W4B + (size_t)(2*n3 + 1)*512 + lane*8), f1, acc4);
    }
    // leaky + scatter valid t1 values to LDS (pads are exact 0, skipped)
    const int mrow = wave*32 + l31;
    #pragma unroll
    for (int r = 0; r < 16; r++) {
        const int n4 = (r & 3) + 8*(r >> 2) + 4*hi;
        if (n4 < 13) {
            float v = acc4[r];
            t1s[mrow*13 + n4] = fmaxf(v, 0.0f) + 0.01f*fminf(v, 0.0f);
        }
    }
    __syncthreads();

    // ---- normalize rows -> T1N [16]-padded bf16 (32B/thread, coalesced) ----
    if (tid < 128) {
        float s = 0.0f, v[13];
        #pragma unroll
        for (int k = 0; k < 13; k++) { v[k] = t1s[tid*13 + k]; s += v[k]*v[k]; }
        const float inv = 1.0f / fmaxf(sqrtf(s), 1e-8f);
        union { __bf16 o[16]; bf16x8 f[2]; } u;
        #pragma unroll
        for (int k = 0; k < 13; k++) u.o[k] = (__bf16)(v[k] * inv);
        #pragma unroll
        for (int k = 13; k < 16; k++) u.o[k] = (__bf16)0.0f;
        bf16x8* dst = reinterpret_cast<bf16x8*>(T1N + (size_t)(bm0 + tid)*16);
        dst[0] = u.f[0];
        dst[1] = u.f[1];
    }
}

// ---------------------------------------------------------------------------
// sim: K=16 32x32 tiles. Wave owns one 32-b-row tile (af = 1 frag), streams
// 32 T1N m-tiles (64-way m-split, grid 1024), 2 tiles/step, max3 reduction.
// ---------------------------------------------------------------------------
__global__ __launch_bounds__(256) void sim_kernel(const char* __restrict__ ws_c,
                                                  float* __restrict__ part) {
    const char* ws = ws_c;
    const __bf16* T1N = (const __bf16*)(ws + OFF_T1N);
    const __bf16* T2N = (const __bf16*)(ws + OFF_T2N);
    const int wave = threadIdx.x >> 6, lane = threadIdx.x & 63;
    const int l31 = lane & 31, hi = lane >> 5;
    const int bgroup = blockIdx.x & 15, ms = blockIdx.x >> 4;   // 16 x 64 grid
    const int b0 = (bgroup*4 + wave) * 32;

    const bf16x8 af = ld8(T2N + (size_t)(b0 + l31)*16 + hi*8);
    const f32x16 zero = {};
    f32x16 mx;
    #pragma unroll
    for (int r = 0; r < 16; r++) mx[r] = -3.0e38f;

    #pragma unroll 4
    for (int mt = ms; mt < 2048; mt += 128) {
        bf16x8 bf0 = ld8(T1N + ((size_t)mt*32 + l31)*16 + hi*8);
        bf16x8 bf1 = ld8(T1N + ((size_t)(mt + 64)*32 + l31)*16 + hi*8);
        f32x16 d0 = mfma32(af, bf0, zero);
        f32x16 d1 = mfma32(af, bf1, zero);
        #pragma unroll
        for (int r = 0; r < 16; r++)
            mx[r] = fmaxf(mx[r], fmaxf(d0[r], d1[r]));   // -> v_max3_f32
    }
    #pragma unroll
    for (int off = 1; off <= 16; off <<= 1) {
        #pragma unroll
        for (int r = 0; r < 16; r++) mx[r] = fmaxf(mx[r], __shfl_xor(mx[r], off));
    }
    if (l31 == 0) {
        #pragma unroll
        for (int reg = 0; reg < 16; reg++)
            part[ms*2048 + b0 + (reg & 3) + 8*(reg >> 2) + 4*hi] = mx[reg];
    }
}

__global__ void reduce_kernel(const float* __restrict__ part, float* __restrict__ out) {
    int b = blockIdx.x*256 + threadIdx.x;
    if (b < 2048) {
        float m = part[b];
        #pragma unroll
        for (int ms = 1; ms < 64; ms++) m = fmaxf(m, part[ms*2048 + b]);
        out[b] = 23.0f * m;
    }
}

// ---------------------------------------------------------------------------
extern "C" void kernel_launch(void* const* d_in, const int* in_sizes, int n_in,
                              void* d_out, int out_size, void* d_ws, size_t ws_size,
                              hipStream_t stream) {
    const float* memory = (const float*)d_in[0];
    const float* value  = (const float*)d_in[1];
    const float* W1 = (const float*)d_in[2]; const float* b1 = (const float*)d_in[3];
    const float* W2 = (const float*)d_in[4]; const float* b2 = (const float*)d_in[5];
    const float* W3 = (const float*)d_in[6]; const float* b3 = (const float*)d_in[7];
    const float* W4 = (const float*)d_in[8]; const float* b4 = (const float*)d_in[9];
    char* ws = (char*)d_ws;
    float* part = (float*)(ws + OFF_PART);
    float* out = (float*)d_out;

    prep_kernel<<<1164, 256, 0, stream>>>(W1, b1, W2, b2, W3, b3, W4, b4, value, ws);
    mlp_kernel<<<512, 256, 0, stream>>>(memory, ws);
    sim_kernel<<<1024, 256, 0, stream>>>(ws, part);
    reduce_kernel<<<8, 256, 0, stream>>>(part, out);
}